// Round 6
// baseline (706.204 us; speedup 1.0000x reference)
//
#include <hip/hip_runtime.h>
#include <math.h>

#define CH 128
#define ETC 3
#define LN_EPS 1e-5f

typedef unsigned short u16;
typedef unsigned int u32;
typedef __attribute__((ext_vector_type(8))) short short8;
typedef __attribute__((ext_vector_type(4))) float f32x4;

__device__ __forceinline__ u16 f2bf(float f) {
    u32 u = __float_as_uint(f);
    u += 0x7FFFu + ((u >> 16) & 1u);
    return (u16)(u >> 16);
}
__device__ __forceinline__ float bflo(u32 u) { return __uint_as_float(u << 16); }
__device__ __forceinline__ float bfhi(u32 u) { return __uint_as_float(u & 0xFFFF0000u); }

__device__ __forceinline__ f32x4 mfma16(short8 a, short8 b, f32x4 c) {
    return __builtin_amdgcn_mfma_f32_16x16x32_bf16(a, b, c, 0, 0, 0);
}
__device__ __forceinline__ short8 ld8(const u16* p) { return *(const short8*)p; }

// ---------------------------------------------------------------------------
// Pack weights: fp32 -> bf16, swizzled to per-lane MFMA B-fragment order.
// Layout: [mat][s(4)][nt(8)][lane(64)][j(8)]   (mat stride = CH*CH u16)
// mats 0-2: Wp_t | 3-8: (Wl0_t, Wr0_t) pairs | 9-11: Wl[0,t]/3 | 12: sum(Wr[0,t])/3
// | 13-15: Wl[1,t]/3 | 16: sum(Wr[1,t])/3.  Also bls[2][128] = sum_t bl[l,t]/3.
// B fragment: lane(q=lane>>4,c=lane&15) holds B[k=s*32+q*8+j][n=nt*16+c]
// ---------------------------------------------------------------------------
__global__ __launch_bounds__(256) void pack_w(
    const float* __restrict__ Wp, const float* __restrict__ Wl0,
    const float* __restrict__ Wr0, const float* __restrict__ Wl,
    const float* __restrict__ Wr, const float* __restrict__ bl,
    u16* __restrict__ Bswz, float* __restrict__ bls)
{
    if (blockIdx.x == 0) {
        int l = threadIdx.x >> 7, i = threadIdx.x & 127;
        bls[threadIdx.x] = (bl[((size_t)l * ETC + 0) * CH + i] +
                            bl[((size_t)l * ETC + 1) * CH + i] +
                            bl[((size_t)l * ETC + 2) * CH + i]) * (1.f / 3.f);
    }
    int grp = blockIdx.x * 256 + threadIdx.x;   // ((mat*4+s)*8+nt)*64 + lane
    if (grp >= 17 * 2048) return;
    int lane = grp & 63;
    int t1 = grp >> 6;
    int nt = t1 & 7, t2 = t1 >> 3;
    int s = t2 & 3, mat = t2 >> 2;
    int q = lane >> 4, c = lane & 15;
    int nn = nt * 16 + c;

    const float* s0;
    const float* s1 = nullptr;
    const float* s2 = nullptr;
    float scale = 1.f;
    if (mat < 3) {
        s0 = Wp + (size_t)mat * CH * CH;
    } else if (mat < 9) {
        int t = (mat - 3) >> 1;
        s0 = ((mat - 3) & 1) ? Wr0 + (size_t)t * CH * CH : Wl0 + (size_t)t * CH * CH;
    } else {
        int l = (mat < 13) ? 0 : 1;
        int mm = mat - (l ? 13 : 9);
        scale = 1.f / 3.f;
        if (mm < 3) s0 = Wl + ((size_t)l * ETC + mm) * CH * CH;
        else {
            s0 = Wr + ((size_t)l * ETC + 0) * CH * CH;
            s1 = s0 + CH * CH;
            s2 = s1 + CH * CH;
        }
    }
    short8 o;
    #pragma unroll
    for (int j = 0; j < 8; ++j) {
        int k = s * 32 + q * 8 + j;
        float v = s0[(size_t)k * CH + nn];
        if (s1) v += s1[(size_t)k * CH + nn] + s2[(size_t)k * CH + nn];
        o[j] = (short)f2bf(v * scale);
    }
    *(short8*)&Bswz[(size_t)grp * 8] = o;
}

// ---------------------------------------------------------------------------
__global__ __launch_bounds__(256) void cast_x(
    const float* __restrict__ x, u16* __restrict__ xb, int total)
{
    int i = (blockIdx.x * 256 + threadIdx.x) * 8;
    if (i >= total) return;
    short8 o;
    #pragma unroll
    for (int j = 0; j < 8; ++j) o[j] = (short)f2bf(x[i + j]);
    *(short8*)&xb[i] = o;
}

// ---------------------------------------------------------------------------
// Fused layer GEMM: B staged in LDS per mat, RF=2 row-frags (32 rows/wave),
// 128 rows/block, 782 blocks.
// MODE 0: layer0 (6 mats: (Wl0_t,Wr0_t) pairs; per-type L2-rownorm; relu+LN)
// MODE 1: mid (4 mats; +bls; relu+LN -> bf16)
// MODE 2: final (4 mats; +bls; fp32 out)
// MODE 3: proj (1 mat; +bias; relu -> bf16)
// ---------------------------------------------------------------------------
template<int MODE>
__global__ __launch_bounds__(256) void combine_k(
    const u16* __restrict__ agg0, const u16* __restrict__ agg1,
    const u16* __restrict__ agg2, const u16* __restrict__ self,
    const u16* __restrict__ Bs, const float* __restrict__ bias,
    const float* __restrict__ lg, const float* __restrict__ lb,
    u16* __restrict__ outb, float* __restrict__ outf, int nrows)
{
    constexpr int RF = 2;
    __shared__ __align__(16) u16 Bsh[CH * CH];   // 32 KB, one mat
    const int tid = threadIdx.x;
    const int w = tid >> 6, lane = tid & 63;
    const int q = lane >> 4, c = lane & 15;
    const int rbase = (blockIdx.x * 4 + w) * (RF * 16);
    const u16* aggs[3] = {agg0, agg1, agg2};
    constexpr int NM = (MODE == 0) ? 6 : ((MODE == 3) ? 1 : 4);

    f32x4 acc[RF][8] = {};
    f32x4 res[RF][8];   // only used by MODE 0
    if constexpr (MODE == 0) {
        #pragma unroll
        for (int rf = 0; rf < RF; ++rf)
            #pragma unroll
            for (int nt = 0; nt < 8; ++nt) res[rf][nt] = (f32x4){0.f, 0.f, 0.f, 0.f};
    }

    #pragma unroll
    for (int m = 0; m < NM; ++m) {
        // ---- stage B_m into LDS (whole block) ----
        __syncthreads();
        const u16* bsrc = Bs + (size_t)m * CH * CH;
        #pragma unroll
        for (int i = 0; i < 8; ++i)
            *(short8*)&Bsh[(i * 256 + tid) * 8] = ld8(&bsrc[(i * 256 + tid) * 8]);
        __syncthreads();

        const u16* A;
        if constexpr (MODE == 0)      A = (m & 1) ? self : aggs[m >> 1];
        else if constexpr (MODE == 3) A = self;
        else                          A = (m < 3) ? aggs[m] : self;

        #pragma unroll
        for (int s = 0; s < 4; ++s) {
            short8 af[RF];
            #pragma unroll
            for (int rf = 0; rf < RF; ++rf)
                af[rf] = ld8(&A[(size_t)(rbase + rf * 16 + c) * CH + s * 32 + q * 8]);
            #pragma unroll
            for (int nt = 0; nt < 8; ++nt) {
                short8 bv = *(const short8*)&Bsh[((size_t)(s * 8 + nt) * 64 + lane) * 8];
                #pragma unroll
                for (int rf = 0; rf < RF; ++rf)
                    acc[rf][nt] = mfma16(af[rf], bv, acc[rf][nt]);
            }
        }

        if constexpr (MODE == 0) {
            if (m & 1) {   // finished a (Wl0_t, Wr0_t) pair: rownorm + accumulate
                const int t = m >> 1;
                #pragma unroll
                for (int rf = 0; rf < RF; ++rf) {
                    float ss[4] = {0.f, 0.f, 0.f, 0.f};
                    #pragma unroll
                    for (int nt = 0; nt < 8; ++nt) {
                        float bf = bias[t * CH + nt * 16 + c];
                        #pragma unroll
                        for (int r = 0; r < 4; ++r) {
                            float v = acc[rf][nt][r] + bf;
                            acc[rf][nt][r] = v;
                            ss[r] += v * v;
                        }
                    }
                    #pragma unroll
                    for (int msk = 1; msk < 16; msk <<= 1)
                        #pragma unroll
                        for (int r = 0; r < 4; ++r) ss[r] += __shfl_xor(ss[r], msk, 64);
                    float sc[4];
                    #pragma unroll
                    for (int r = 0; r < 4; ++r)
                        sc[r] = 1.f / (3.f * fmaxf(sqrtf(ss[r]), 1e-12f));
                    #pragma unroll
                    for (int nt = 0; nt < 8; ++nt)
                        #pragma unroll
                        for (int r = 0; r < 4; ++r) {
                            res[rf][nt][r] += acc[rf][nt][r] * sc[r];
                            acc[rf][nt][r] = 0.f;
                        }
                }
            }
        }
    }

    if constexpr (MODE != 0) {
        // fold bias into acc (no separate res bank)
        #pragma unroll
        for (int nt = 0; nt < 8; ++nt) {
            float bv = bias[nt * 16 + c];
            #pragma unroll
            for (int rf = 0; rf < RF; ++rf)
                #pragma unroll
                for (int r = 0; r < 4; ++r) acc[rf][nt][r] += bv;
        }
    }

    if constexpr (MODE == 2) {
        #pragma unroll
        for (int rf = 0; rf < RF; ++rf)
            #pragma unroll
            for (int nt = 0; nt < 8; ++nt)
                #pragma unroll
                for (int r = 0; r < 4; ++r) {
                    int row = rbase + rf * 16 + q * 4 + r;
                    if (row < nrows) outf[(size_t)row * CH + nt * 16 + c] = acc[rf][nt][r];
                }
        return;
    }

    if constexpr (MODE == 3) {
        #pragma unroll
        for (int rf = 0; rf < RF; ++rf)
            #pragma unroll
            for (int nt = 0; nt < 8; ++nt)
                #pragma unroll
                for (int r = 0; r < 4; ++r) {
                    int row = rbase + rf * 16 + q * 4 + r;
                    outb[(size_t)row * CH + nt * 16 + c] = f2bf(fmaxf(acc[rf][nt][r], 0.f));
                }
        return;
    }

    // MODE 0/1: relu + LayerNorm, per row-frag. bank = res (MODE0) or acc (MODE1).
    auto& bank = (MODE == 0) ? res : acc;
    #pragma unroll
    for (int rf = 0; rf < RF; ++rf) {
        float s1[4] = {0.f, 0.f, 0.f, 0.f}, s2[4] = {0.f, 0.f, 0.f, 0.f};
        #pragma unroll
        for (int nt = 0; nt < 8; ++nt)
            #pragma unroll
            for (int r = 0; r < 4; ++r) {
                float v = fmaxf(bank[rf][nt][r], 0.f);
                bank[rf][nt][r] = v;
                s1[r] += v;
                s2[r] += v * v;
            }
        #pragma unroll
        for (int msk = 1; msk < 16; msk <<= 1)
            #pragma unroll
            for (int r = 0; r < 4; ++r) {
                s1[r] += __shfl_xor(s1[r], msk, 64);
                s2[r] += __shfl_xor(s2[r], msk, 64);
            }
        float mu[4], rs[4];
        #pragma unroll
        for (int r = 0; r < 4; ++r) {
            mu[r] = s1[r] * (1.f / 128.f);
            float var = s2[r] * (1.f / 128.f) - mu[r] * mu[r];
            rs[r] = rsqrtf(var + LN_EPS);
        }
        #pragma unroll
        for (int nt = 0; nt < 8; ++nt) {
            float gv = lg[nt * 16 + c], bv = lb[nt * 16 + c];
            #pragma unroll
            for (int r = 0; r < 4; ++r) {
                int row = rbase + rf * 16 + q * 4 + r;
                outb[(size_t)row * CH + nt * 16 + c] =
                    f2bf((bank[rf][nt][r] - mu[r]) * rs[r] * gv + bv);
            }
        }
    }
}

// ---------------------------------------------------------------------------
// CSR gather-mean (bf16): half-wave (32 lanes) per node, uint2 per lane,
// 4-edge unroll with 4 accumulator banks. t = blockIdx.y (strided pointers).
// ---------------------------------------------------------------------------
__global__ __launch_bounds__(256) void agg_k(
    const u16* __restrict__ msg, const int* __restrict__ rowptr,
    const int* __restrict__ col, u16* __restrict__ agg, int n,
    int Ecap, unsigned long long aggstride)
{
    const int t = blockIdx.y;
    rowptr += (size_t)t * (n + 1);
    col += (size_t)t * Ecap;
    agg += (size_t)t * aggstride;

    int gid = blockIdx.x * 256 + threadIdx.x;
    int node = gid >> 5;
    int lane = threadIdx.x & 31;
    if (node >= n) return;
    int s = rowptr[node], e = rowptr[node + 1];
    const uint2* m64 = (const uint2*)msg;   // row = 32 uint2
    float a0 = 0.f, a1 = 0.f, a2 = 0.f, a3 = 0.f;
    float b0 = 0.f, b1 = 0.f, b2 = 0.f, b3 = 0.f;
    float c0 = 0.f, c1 = 0.f, c2 = 0.f, c3 = 0.f;
    float d0 = 0.f, d1 = 0.f, d2 = 0.f, d3 = 0.f;
    int j = s;
    for (; j + 4 <= e; j += 4) {
        int i0 = col[j], i1 = col[j + 1], i2 = col[j + 2], i3 = col[j + 3];
        uint2 v0 = m64[(size_t)i0 * 32 + lane];
        uint2 v1 = m64[(size_t)i1 * 32 + lane];
        uint2 v2 = m64[(size_t)i2 * 32 + lane];
        uint2 v3 = m64[(size_t)i3 * 32 + lane];
        a0 += bflo(v0.x); a1 += bfhi(v0.x); a2 += bflo(v0.y); a3 += bfhi(v0.y);
        b0 += bflo(v1.x); b1 += bfhi(v1.x); b2 += bflo(v1.y); b3 += bfhi(v1.y);
        c0 += bflo(v2.x); c1 += bfhi(v2.x); c2 += bflo(v2.y); c3 += bfhi(v2.y);
        d0 += bflo(v3.x); d1 += bfhi(v3.x); d2 += bflo(v3.y); d3 += bfhi(v3.y);
    }
    for (; j < e; ++j) {
        int i0 = col[j];
        uint2 v0 = m64[(size_t)i0 * 32 + lane];
        a0 += bflo(v0.x); a1 += bfhi(v0.x); a2 += bflo(v0.y); a3 += bfhi(v0.y);
    }
    a0 += b0 + c0 + d0; a1 += b1 + c1 + d1; a2 += b2 + c2 + d2; a3 += b3 + c3 + d3;
    float inv = 1.f / (float)max(e - s, 1);
    uint2 o;
    o.x = (u32)f2bf(a0 * inv) | ((u32)f2bf(a1 * inv) << 16);
    o.y = (u32)f2bf(a2 * inv) | ((u32)f2bf(a3 * inv) << 16);
    ((uint2*)agg)[(size_t)node * 32 + lane] = o;
}

// ---------------------------------------------------------------------------
// CSR construction
// ---------------------------------------------------------------------------
__global__ __launch_bounds__(256) void hist_k(
    const int* __restrict__ edges, int* __restrict__ cnt, int E, int n)
{
    int t = blockIdx.y;
    int e = blockIdx.x * 256 + threadIdx.x;
    if (e >= E) return;
    int dst = edges[(size_t)t * 2 * E + E + e];
    atomicAdd(&cnt[t * n + dst], 1);
}

__global__ __launch_bounds__(256) void scan1_k(
    const int* __restrict__ cnt, int* __restrict__ bsum, int n, int nbs)
{
    int t = blockIdx.y, b = blockIdx.x;
    int i = b * 256 + threadIdx.x;
    int v = (i < n) ? cnt[t * n + i] : 0;
    #pragma unroll
    for (int m = 1; m < 64; m <<= 1) v += __shfl_xor(v, m, 64);
    __shared__ int wsum[4];
    if ((threadIdx.x & 63) == 0) wsum[threadIdx.x >> 6] = v;
    __syncthreads();
    if (threadIdx.x == 0) bsum[t * nbs + b] = wsum[0] + wsum[1] + wsum[2] + wsum[3];
}

__global__ __launch_bounds__(512) void scan2_k(int* __restrict__ bsum, int nbs, int nb)
{
    int t = blockIdx.x;
    int tid = threadIdx.x;
    __shared__ int sh[512];
    int v = (tid < nb) ? bsum[t * nbs + tid] : 0;
    sh[tid] = v;
    __syncthreads();
    for (int off = 1; off < 512; off <<= 1) {
        int x = (tid >= off) ? sh[tid - off] : 0;
        __syncthreads();
        sh[tid] += x;
        __syncthreads();
    }
    if (tid < nb) bsum[t * nbs + tid] = sh[tid] - v;
}

__global__ __launch_bounds__(256) void scan3_k(
    const int* __restrict__ cnt, const int* __restrict__ bsum,
    int* __restrict__ rowptr, int n, int nbs)
{
    int t = blockIdx.y, b = blockIdx.x;
    int tid = threadIdx.x;
    int i = b * 256 + tid;
    __shared__ int sh[256];
    int v = (i < n) ? cnt[t * n + i] : 0;
    sh[tid] = v;
    __syncthreads();
    for (int off = 1; off < 256; off <<= 1) {
        int x = (tid >= off) ? sh[tid - off] : 0;
        __syncthreads();
        sh[tid] += x;
        __syncthreads();
    }
    int excl = sh[tid] - v + bsum[t * nbs + b];
    if (i < n) rowptr[(size_t)t * (n + 1) + i] = excl;
    if (i == n - 1) rowptr[(size_t)t * (n + 1) + n] = excl + v;
}

__global__ __launch_bounds__(256) void fill_k(
    const int* __restrict__ edges, const int* __restrict__ rowptr,
    int* __restrict__ cnt2, int* __restrict__ colbuf, int E, int n)
{
    int t = blockIdx.y;
    int e = blockIdx.x * 256 + threadIdx.x;
    if (e >= E) return;
    int src = edges[(size_t)t * 2 * E + e];
    int dst = edges[(size_t)t * 2 * E + E + e];
    int pos = rowptr[(size_t)t * (n + 1) + dst] + atomicAdd(&cnt2[t * n + dst], 1);
    colbuf[(size_t)t * E + pos] = src;
}

// ---------------------------------------------------------------------------
extern "C" void kernel_launch(void* const* d_in, const int* in_sizes, int n_in,
                              void* d_out, int out_size, void* d_ws, size_t ws_size,
                              hipStream_t stream) {
    const float* x    = (const float*)d_in[0];
    const int*   edges= (const int*)d_in[1];
    const float* Wp   = (const float*)d_in[2];
    const float* bp   = (const float*)d_in[3];
    const float* Wl0  = (const float*)d_in[4];
    const float* bl0  = (const float*)d_in[5];
    const float* Wr0  = (const float*)d_in[6];
    const float* Wl   = (const float*)d_in[7];
    const float* bl   = (const float*)d_in[8];
    const float* Wr   = (const float*)d_in[9];
    const float* ln_g = (const float*)d_in[10];
    const float* ln_b = (const float*)d_in[11];
    float* out = (float*)d_out;

    const int n  = in_sizes[0] / CH;         // 100000
    const int E  = in_sizes[1] / (2 * ETC);  // 500000
    const int npad = ((n + 127) / 128) * 128;
    const int NBS = 512;
    const int nb = (n + 255) / 256;
    const size_t MS = (size_t)CH * CH;       // mat stride in u16

    // workspace layout
    char* p = (char*)d_ws;
    u16* xb   = (u16*)p;  p += (size_t)npad * CH * 2;
    u16* hs   = (u16*)p;  p += (size_t)npad * CH * 2;
    u16* agg  = (u16*)p;  p += (size_t)ETC * npad * CH * 2;
    u16* Bswz = (u16*)p;  p += 17 * MS * 2;
    float* bls = (float*)p; p += 256 * 4;
    int* cnt    = (int*)p;  p += (size_t)ETC * n * 4;
    int* rowptr = (int*)p;  p += (size_t)ETC * (n + 1) * 4;
    int* colbuf = (int*)p;  p += (size_t)ETC * E * 4;
    int* bsum   = (int*)p;

    const dim3 b256(256);
    const dim3 ge((E + 255) / 256, ETC);
    const dim3 gs(nb, ETC);
    const int gb = (n + 127) / 128;          // 782 blocks, 128 rows each
    const int ga = (n * 32 + 255) / 256;     // agg blocks (half-wave/node)

    // ---- CSR build ----
    hipMemsetAsync(cnt, 0, (size_t)ETC * n * sizeof(int), stream);
    hist_k<<<ge, b256, 0, stream>>>(edges, cnt, E, n);
    scan1_k<<<gs, b256, 0, stream>>>(cnt, bsum, n, NBS);
    scan2_k<<<ETC, 512, 0, stream>>>(bsum, NBS, nb);
    scan3_k<<<gs, b256, 0, stream>>>(cnt, bsum, rowptr, n, NBS);
    hipMemsetAsync(cnt, 0, (size_t)ETC * n * sizeof(int), stream);
    fill_k<<<ge, b256, 0, stream>>>(edges, rowptr, cnt, colbuf, E, n);

    // ---- pack weights + cast x ----
    pack_w<<<136, b256, 0, stream>>>(Wp, Wl0, Wr0, Wl, Wr, bl, Bswz, bls);
    cast_x<<<(n * CH / 8 + 255) / 256, b256, 0, stream>>>(x, xb, n * CH);

    // ---- layer 0: per-type proj + gather; then fused combine ----
    for (int t = 0; t < ETC; ++t) {
        combine_k<3><<<gb, b256, 0, stream>>>(
            nullptr, nullptr, nullptr, xb, Bswz + (size_t)t * MS, bp + t * CH,
            nullptr, nullptr, hs, nullptr, n);
        agg_k<<<dim3(ga, 1), b256, 0, stream>>>(hs, rowptr + (size_t)t * (n + 1),
                                                colbuf + (size_t)t * E,
                                                agg + (size_t)t * npad * CH, n, 0, 0ull);
    }
    combine_k<0><<<gb, b256, 0, stream>>>(agg, agg + (size_t)npad * CH,
                                          agg + (size_t)2 * npad * CH, xb,
                                          Bswz + 3 * MS, bl0, ln_g, ln_b, hs, nullptr, n);

    // ---- layer 1 ----
    agg_k<<<dim3(ga, ETC), b256, 0, stream>>>(hs, rowptr, colbuf, agg, n, E,
                                              (unsigned long long)npad * CH);
    combine_k<1><<<gb, b256, 0, stream>>>(agg, agg + (size_t)npad * CH,
                                          agg + (size_t)2 * npad * CH, hs,
                                          Bswz + 9 * MS, bls, ln_g + CH, ln_b + CH,
                                          hs, nullptr, n);

    // ---- layer 2 (final, fp32 out) ----
    agg_k<<<dim3(ga, ETC), b256, 0, stream>>>(hs, rowptr, colbuf, agg, n, E,
                                              (unsigned long long)npad * CH);
    combine_k<2><<<gb, b256, 0, stream>>>(agg, agg + (size_t)npad * CH,
                                          agg + (size_t)2 * npad * CH, hs,
                                          Bswz + 13 * MS, bls + CH, nullptr, nullptr,
                                          nullptr, out, n);
}